// Round 14
// baseline (1890.122 us; speedup 1.0000x reference)
//
#include <hip/hip_runtime.h>
#include <hip/hip_bf16.h>
#include <stdint.h>

typedef __bf16 bf16;
typedef __bf16 bf16x8 __attribute__((ext_vector_type(8)));
typedef float f32x4 __attribute__((ext_vector_type(4)));

typedef uint32_t __attribute__((address_space(1))) * gptr_as1;
typedef uint32_t __attribute__((address_space(3))) * lptr_as3;

__device__ __forceinline__ void async16(const void* g, void* l) {
    __builtin_amdgcn_global_load_lds((gptr_as1)(uintptr_t)g,
                                     (lptr_as3)(uintptr_t)l,
                                     16, 0, 0);
}

__device__ __forceinline__ void bar() {
    asm volatile("" ::: "memory");
    __builtin_amdgcn_s_barrier();
    asm volatile("" ::: "memory");
}

// ---------------------------------------------------------------- cvt f32->bf16
__global__ void cvt_f32_bf16_kernel(const float* __restrict__ src,
                                    bf16* __restrict__ dst, int n8) {
    int i = blockIdx.x * blockDim.x + threadIdx.x;
    if (i >= n8) return;
    const float4* s = reinterpret_cast<const float4*>(src);
    float4 a = s[2 * (size_t)i], b = s[2 * (size_t)i + 1];
    bf16x8 v;
    v[0] = (bf16)a.x; v[1] = (bf16)a.y; v[2] = (bf16)a.z; v[3] = (bf16)a.w;
    v[4] = (bf16)b.x; v[5] = (bf16)b.y; v[6] = (bf16)b.z; v[7] = (bf16)b.w;
    *reinterpret_cast<bf16x8*>(dst + (size_t)i * 8) = v;
}

// cvt + 16-row interleave: src row r (of DHID) -> dst row (r/16)*32 + sel*16 + r%16.
__global__ void cvt_ilv_kernel(const float* __restrict__ src,
                               bf16* __restrict__ dst, int n8, int sel) {
    int i = blockIdx.x * blockDim.x + threadIdx.x;
    if (i >= n8) return;
    const int row = i >> 8;          // / 256  (DIN=2048 -> 256 chunks/row)
    const int c = i & 255;
    const int drow = ((row >> 4) << 5) + (sel << 4) + (row & 15);
    const float4* s = reinterpret_cast<const float4*>(src);
    float4 a = s[2 * (size_t)i], b = s[2 * (size_t)i + 1];
    bf16x8 v;
    v[0] = (bf16)a.x; v[1] = (bf16)a.y; v[2] = (bf16)a.z; v[3] = (bf16)a.w;
    v[4] = (bf16)b.x; v[5] = (bf16)b.y; v[6] = (bf16)b.z; v[7] = (bf16)b.w;
    *reinterpret_cast<bf16x8*>(dst + ((size_t)drow * 256 + c) * 8) = v;
}

// ---------------------------------------------------------------- NEW: 256x128 BK=32, 2 blocks/CU, dbuf (TLP overlap)
// C = A[M,K]*B[N,K]^T. 256 thr / 4 waves (2x2), wave tile 128x64 (optimal
// 23KB-LDS-read/MFLOP ratio), acc[8][4]=128 regs. LDS dbuf x (A[256][32] 16K +
// B[128][32] 8K) = 48KB/block -> 2 blocks/CU (96KB), __launch_bounds__(256,2)
// -> VGPR cap 256 (est ~210, no spill).
// Per tile: [stage kt+1 (6 gloads, issued FIRST) -> 12 ds_read_b128 -> lgkm0
// -> 32 MFMA (one per acc elem) -> vmcnt(0) (loads a full tile old, ~free)
// -> bar]. The co-resident second block anti-phases: its MFMA overlaps this
// block's read/stage bursts (m114) — the overlap barriers forbid in-block.
// WAR: stage(kt+1) targets buffer !(kt&1), whose tile-(kt-1) reads were
//      lgkm-retired before each wave passed bar(kt-1), which precedes this
//      stage in program order. RAW: stage(kt) drained by vmcnt(0)+bar at end
//      of kt-1, before any read of buffer kt&1.
// 64B-row-pitch swizzle (bank-derived): col ^= ((row>>1)&3)<<4 -> 16 lanes
// spread over 8 bank-quads, 2/quad = conflict-free; gload source uses the
// matching involution slot^((row>>1)&3), LDS dest linear (rule 21).
// EPI=0: bf16(gelu(acc*s1)) | EPI=1: f32(acc*s1) | EPI=2: swiglu, 16-col interleave.
template <int EPI, int K>
__global__ __launch_bounds__(256, 2)
void gemm2t(const bf16* __restrict__ A, const bf16* __restrict__ B,
            void* __restrict__ Cout, const float* __restrict__ s1p,
            const float* __restrict__ s2p, int N, int ldh) {
    __shared__ __align__(16) char sm[49152];

    const int tid = threadIdx.x;
    const int w = tid >> 6, l = tid & 63;
    const int wr = w >> 1, wc = w & 1;   // 2x2 wave grid; wave tile 128x64

    const int gx = gridDim.x;            // N/128
    const int nwg = gx * (int)gridDim.y;
    const int orig = blockIdx.y * gx + blockIdx.x;
    const int wg = (orig & 7) * (nwg >> 3) + (orig >> 3);
    const int bm = wg / gx, bn = wg % gx;

    constexpr int NT = K / 32;

    f32x4 acc[8][4] = {};

    const int arow = bm * 256, brow = bn * 128;

    // per-lane persistent staging pointers (one per 64-row slab), +64B/tile
    const int sr = l >> 2;                               // row within wave's 16
    const int sg = ((l & 3) ^ ((l >> 3) & 3)) << 4;      // slot ^ ((row>>1)&3)
    const char* qa0 = (const char*)(A + (size_t)(arow +   0 + w * 16 + sr) * K) + sg;
    const char* qa1 = (const char*)(A + (size_t)(arow +  64 + w * 16 + sr) * K) + sg;
    const char* qa2 = (const char*)(A + (size_t)(arow + 128 + w * 16 + sr) * K) + sg;
    const char* qa3 = (const char*)(A + (size_t)(arow + 192 + w * 16 + sr) * K) + sg;
    const char* qb0 = (const char*)(B + (size_t)(brow +   0 + w * 16 + sr) * K) + sg;
    const char* qb1 = (const char*)(B + (size_t)(brow +  64 + w * 16 + sr) * K) + sg;
    const int ldw = w * 1024;            // 16 rows x 64B per wave

    auto STAGE_TILE = [&](int p) {       // stage current pointers into buffer p
        char* ba = sm + p * 24576;
        char* bb = ba + 16384;
        async16(qa0, ba +     0 + ldw); async16(qa1, ba +  4096 + ldw);
        async16(qa2, ba +  8192 + ldw); async16(qa3, ba + 12288 + ldw);
        async16(qb0, bb +     0 + ldw); async16(qb1, bb +  4096 + ldw);
    };
    auto ADV = [&]() {
        qa0 += 64; qa1 += 64; qa2 += 64; qa3 += 64; qb0 += 64; qb1 += 64;
    };

    const int rlane = l & 15;
    const int chi = (l >> 4) << 4;

    // ---- prologue: tile0 -> buf0
    STAGE_TILE(0);
    ADV();
    asm volatile("s_waitcnt vmcnt(0)" ::: "memory");
    bar();

#pragma unroll 1
    for (int kt = 0; kt < NT; ++kt) {
        if (kt + 1 < NT) { STAGE_TILE((kt + 1) & 1); ADV(); }
        const char* ba = sm + (kt & 1) * 24576;
        const char* bb = ba + 16384;

        bf16x8 av[8], bv[4];
#pragma unroll
        for (int i = 0; i < 8; ++i) {
            const int row = wr * 128 + i * 16 + rlane;
            av[i] = *reinterpret_cast<const bf16x8*>(
                ba + row * 64 + (chi ^ (((row >> 1) & 3) << 4)));
        }
#pragma unroll
        for (int j = 0; j < 4; ++j) {
            const int row = wc * 64 + j * 16 + rlane;
            bv[j] = *reinterpret_cast<const bf16x8*>(
                bb + row * 64 + (chi ^ (((row >> 1) & 3) << 4)));
        }
        asm volatile("s_waitcnt lgkmcnt(0)" ::: "memory");
        __builtin_amdgcn_sched_barrier(0);
        __builtin_amdgcn_s_setprio(1);
#pragma unroll
        for (int i = 0; i < 8; ++i)
#pragma unroll
            for (int j = 0; j < 4; ++j)
                acc[i][j] = __builtin_amdgcn_mfma_f32_16x16x32_bf16(av[i], bv[j], acc[i][j], 0, 0, 0);
        __builtin_amdgcn_s_setprio(0);
        asm volatile("s_waitcnt vmcnt(0)" ::: "memory");
        bar();
    }

    const float s1 = s1p[0];
    const int r0 = bm * 256 + wr * 128 + ((l >> 4) << 2);
    if constexpr (EPI == 2) {
        const float s2 = s2p[0];
        const int hcb = (bn * 4 + wc * 2) * 16 + rlane;
#pragma unroll
        for (int i = 0; i < 8; ++i)
#pragma unroll
            for (int jp = 0; jp < 2; ++jp)
#pragma unroll
                for (int q = 0; q < 4; ++q) {
                    float g = acc[i][2 * jp][q] * s1;
                    float v = acc[i][2 * jp + 1][q] * s2;
                    float sig = 1.0f / (1.0f + __expf(-g));
                    ((bf16*)Cout)[(size_t)(r0 + i * 16 + q) * ldh + hcb + jp * 16] =
                        (bf16)(g * sig * v);
                }
    } else {
        const int c0 = bn * 128 + wc * 64 + rlane;
#pragma unroll
        for (int i = 0; i < 8; ++i)
#pragma unroll
            for (int j = 0; j < 4; ++j)
#pragma unroll
                for (int q = 0; q < 4; ++q) {
                    float v = acc[i][j][q] * s1;
                    size_t idx = (size_t)(r0 + i * 16 + q) * N + (c0 + j * 16);
                    if constexpr (EPI == 0) {
                        float g = 0.5f * v * (1.0f + erff(v * 0.70710678118654752f));
                        ((bf16*)Cout)[idx] = (bf16)g;
                    } else {
                        ((float*)Cout)[idx] = v;
                    }
                }
    }
}

// ---------------------------------------------------------------- R13 proven 256^2 8-phase kernel (GEMM12 / GEMM3)
template <int EPI, int K>
__global__ __launch_bounds__(512, 1)
void gemm8p(const bf16* __restrict__ A, const bf16* __restrict__ B,
            void* __restrict__ Cout, const float* __restrict__ s1p,
            const float* __restrict__ s2p, int N, int ldh) {
    __shared__ __align__(16) char sm[131072];

    const int tid = threadIdx.x;
    const int w = tid >> 6, l = tid & 63;
    const int wr = w >> 2, wc = w & 3;

    const int gx = gridDim.x;
    const int nwg = gx * (int)gridDim.y;
    const int orig = blockIdx.y * gx + blockIdx.x;
    const int wg = (orig & 7) * (nwg >> 3) + (orig >> 3);
    const int bm = wg / gx, bn = wg % gx;

    constexpr int NT = K / 64;

    f32x4 acc[8][4] = {};

    char* const bufA0 = sm;
    char* const bufB0 = sm + 32768;
    char* const bufA1 = sm + 65536;
    char* const bufB1 = sm + 98304;
    const int arow = bm * 256, brow = bn * 256;

    const int srow_in = l >> 3;
    const int scolb = ((l & 7) ^ srow_in) << 4;
    auto STAGE = [&](char* ldsT, const bf16* g, int grow0, int kt, int r0) {
        const int rr = r0 + w * 8 + srow_in;
        const char* gp = (const char*)(g + (size_t)(grow0 + rr) * K + kt * 64) + scolb;
        async16(gp, ldsT + r0 * 128 + w * 1024);
    };

    const int rlane = l & 15;
    const int chi = (l >> 4) << 4;
    const int sw = (rlane & 7) << 4;
    const int ksd = (rlane & 4) ? -64 : 64;
    const int offA = (wr * 128 + rlane) * 128 + (chi ^ sw);
    const int offB = (wc * 64 + rlane) * 128 + (chi ^ sw);
    const char* const pA0  = bufA0 + offA;  const char* const pA0k = pA0 + ksd;
    const char* const pB0  = bufB0 + offB;  const char* const pB0k = pB0 + ksd;
    const char* const pA1  = bufA1 + offA;  const char* const pA1k = pA1 + ksd;
    const char* const pB1  = bufB1 + offB;  const char* const pB1k = pB1 + ksd;

    STAGE(bufA0, A, arow, 0, 0);   STAGE(bufA0, A, arow, 0, 128);
    STAGE(bufB0, B, brow, 0, 0);   STAGE(bufB0, B, brow, 0, 64);
    STAGE(bufB0, B, brow, 0, 128); STAGE(bufB0, B, brow, 0, 192);
    STAGE(bufA0, A, arow, 0, 64);  STAGE(bufA0, A, arow, 0, 192);
    STAGE(bufA1, A, arow, 1, 0);   STAGE(bufA1, A, arow, 1, 128);
    STAGE(bufB1, B, brow, 1, 0);   STAGE(bufB1, B, brow, 1, 64);
    STAGE(bufB1, B, brow, 1, 128); STAGE(bufB1, B, brow, 1, 192);
    asm volatile("s_waitcnt vmcnt(6)" ::: "memory");
    bar();

    auto body = [&](int kt, char* cA, char* cB, char* nA,
                    const char* pa, const char* pak,
                    const char* pb, const char* pbk) {
        bf16x8 ae[4], ao[4], bv[4];
#pragma unroll
        for (int i = 0; i < 4; ++i)
            ae[i] = *reinterpret_cast<const bf16x8*>(pa + i * 2048);
#pragma unroll
        for (int j = 0; j < 4; ++j)
            bv[j] = *reinterpret_cast<const bf16x8*>(pb + j * 2048);
        if (kt + 1 < NT) { STAGE(nA, A, arow, kt + 1, 64); STAGE(nA, A, arow, kt + 1, 192); }
        bar();
        asm volatile("s_waitcnt lgkmcnt(0)" ::: "memory");
        __builtin_amdgcn_sched_barrier(0);
        __builtin_amdgcn_s_setprio(1);
#pragma unroll
        for (int i = 0; i < 4; ++i)
#pragma unroll
            for (int j = 0; j < 4; ++j)
                acc[i][j] = __builtin_amdgcn_mfma_f32_16x16x32_bf16(ae[i], bv[j], acc[i][j], 0, 0, 0);
        __builtin_amdgcn_s_setprio(0);
        bar();
#pragma unroll
        for (int i = 0; i < 4; ++i)
            ao[i] = *reinterpret_cast<const bf16x8*>(pa + 8192 + i * 2048);
        bar();
        asm volatile("s_waitcnt lgkmcnt(0)" ::: "memory");
        __builtin_amdgcn_sched_barrier(0);
        __builtin_amdgcn_s_setprio(1);
#pragma unroll
        for (int i = 0; i < 4; ++i)
#pragma unroll
            for (int j = 0; j < 4; ++j)
                acc[4 + i][j] = __builtin_amdgcn_mfma_f32_16x16x32_bf16(ao[i], bv[j], acc[4 + i][j], 0, 0, 0);
        __builtin_amdgcn_s_setprio(0);
        bar();
#pragma unroll
        for (int i = 0; i < 4; ++i)
            ae[i] = *reinterpret_cast<const bf16x8*>(pak + i * 2048);
#pragma unroll
        for (int j = 0; j < 4; ++j)
            bv[j] = *reinterpret_cast<const bf16x8*>(pbk + j * 2048);
        if (kt + 2 < NT) { STAGE(cB, B, brow, kt + 2, 0); STAGE(cB, B, brow, kt + 2, 64); }
        bar();
        asm volatile("s_waitcnt lgkmcnt(0)" ::: "memory");
        __builtin_amdgcn_sched_barrier(0);
        __builtin_amdgcn_s_setprio(1);
#pragma unroll
        for (int i = 0; i < 4; ++i)
#pragma unroll
            for (int j = 0; j < 4; ++j)
                acc[i][j] = __builtin_amdgcn_mfma_f32_16x16x32_bf16(ae[i], bv[j], acc[i][j], 0, 0, 0);
        __builtin_amdgcn_s_setprio(0);
        bar();
#pragma unroll
        for (int i = 0; i < 4; ++i)
            ao[i] = *reinterpret_cast<const bf16x8*>(pak + 8192 + i * 2048);
        if (kt + 2 < NT) {
            STAGE(cB, B, brow, kt + 2, 128); STAGE(cB, B, brow, kt + 2, 192);
            STAGE(cA, A, arow, kt + 2, 0);   STAGE(cA, A, arow, kt + 2, 128);
        }
        bar();
        asm volatile("s_waitcnt lgkmcnt(0)" ::: "memory");
        __builtin_amdgcn_sched_barrier(0);
        __builtin_amdgcn_s_setprio(1);
#pragma unroll
        for (int i = 0; i < 4; ++i)
#pragma unroll
            for (int j = 0; j < 4; ++j)
                acc[4 + i][j] = __builtin_amdgcn_mfma_f32_16x16x32_bf16(ao[i], bv[j], acc[4 + i][j], 0, 0, 0);
        __builtin_amdgcn_s_setprio(0);
        if (kt == NT - 2) { asm volatile("s_waitcnt vmcnt(0)" ::: "memory"); }
        else              { asm volatile("s_waitcnt vmcnt(6)" ::: "memory"); }
        bar();
    };

#pragma unroll 1
    for (int kt = 0; kt < NT; kt += 2) {
        body(kt,     bufA0, bufB0, bufA1, pA0, pA0k, pB0, pB0k);
        body(kt + 1, bufA1, bufB1, bufA0, pA1, pA1k, pB1, pB1k);
    }

    const float s1 = s1p[0];
    const int r0 = bm * 256 + wr * 128 + ((l >> 4) << 2);
    if constexpr (EPI == 2) {
        const float s2 = s2p[0];
        const int hcb = (bn * 8 + wc * 2) * 16 + rlane;
#pragma unroll
        for (int i = 0; i < 8; ++i)
#pragma unroll
            for (int jp = 0; jp < 2; ++jp)
#pragma unroll
                for (int q = 0; q < 4; ++q) {
                    float g = acc[i][2 * jp][q] * s1;
                    float v = acc[i][2 * jp + 1][q] * s2;
                    float sig = 1.0f / (1.0f + __expf(-g));
                    ((bf16*)Cout)[(size_t)(r0 + i * 16 + q) * ldh + hcb + jp * 16] =
                        (bf16)(g * sig * v);
                }
    } else {
        const int c0 = bn * 256 + wc * 64 + rlane;
#pragma unroll
        for (int i = 0; i < 8; ++i)
#pragma unroll
            for (int j = 0; j < 4; ++j)
#pragma unroll
                for (int q = 0; q < 4; ++q) {
                    float v = acc[i][j][q] * s1;
                    size_t idx = (size_t)(r0 + i * 16 + q) * N + (c0 + j * 16);
                    if constexpr (EPI == 0) {
                        float g = 0.5f * v * (1.0f + erff(v * 0.70710678118654752f));
                        ((bf16*)Cout)[idx] = (bf16)g;
                    } else {
                        ((float*)Cout)[idx] = v;
                    }
                }
    }
}

// ---------------------------------------------------------------- launch
extern "C" void kernel_launch(void* const* d_in, const int* in_sizes, int n_in,
                              void* d_out, int out_size, void* d_ws, size_t ws_size,
                              hipStream_t stream) {
    constexpr int NTOK = 8192, DIN = 2048, DHID = 8192;

    const float* x  = (const float*)d_in[0];
    const float* W1 = (const float*)d_in[1];
    const float* W2 = (const float*)d_in[2];
    const float* Wh = (const float*)d_in[3];
    const float* W3 = (const float*)d_in[4];
    const float* s1 = (const float*)d_in[5];
    const float* s2 = (const float*)d_in[6];
    const float* sh = (const float*)d_in[7];
    const float* s3 = (const float*)d_in[8];
    float* out = (float*)d_out;

    char* ws = (char*)d_ws;
    size_t off = 0;
    bf16* xb   = (bf16*)(ws + off); off += (size_t)NTOK * DIN * 2;
    bf16* w12b = (bf16*)(ws + off); off += (size_t)2 * DHID * DIN * 2;
    bf16* w3b  = (bf16*)(ws + off); off += (size_t)DIN * DHID * 2;
    bf16* whb  = (bf16*)(ws + off); off += (size_t)DHID * DHID * 2;
    bf16* h1   = (bf16*)(ws + off); off += (size_t)NTOK * DHID * 2;
    bf16* h2   = (bf16*)(ws + off); off += (size_t)NTOK * DHID * 2;
    if (ws_size < off) return;

    auto cvt = [&](const float* s, bf16* d, size_t n) {
        int n8 = (int)(n / 8);
        cvt_f32_bf16_kernel<<<(n8 + 255) / 256, 256, 0, stream>>>(s, d, n8);
    };
    cvt(x,  xb,  (size_t)NTOK * DIN);
    cvt(Wh, whb, (size_t)DHID * DHID);
    cvt(W3, w3b, (size_t)DIN * DHID);
    {
        int n8 = (int)((size_t)DHID * DIN / 8);
        cvt_ilv_kernel<<<(n8 + 255) / 256, 256, 0, stream>>>(W1, w12b, n8, 0);
        cvt_ilv_kernel<<<(n8 + 255) / 256, 256, 0, stream>>>(W2, w12b, n8, 1);
    }

    // GEMM1+2 fused (proven gemm8p): C[8192, 16384] -> swiglu -> h1
    gemm8p<2, DIN><<<dim3(2 * DHID / 256, NTOK / 256), 512, 0, stream>>>(
        xb, w12b, h1, s1, s2, 2 * DHID, DHID);
    // hidden GEMM + gelu -> h2  (NEW 2-block TLP kernel — A/B bisect)
    gemm2t<0, DHID><<<dim3(DHID / 128, NTOK / 256), 256, 0, stream>>>(
        h1, whb, h2, sh, sh, DHID, DHID);
    // output GEMM -> out (f32) (proven gemm8p)
    gemm8p<1, DHID><<<dim3(DIN / 256, NTOK / 256), 512, 0, stream>>>(
        h2, w3b, out, s3, s3, DIN, DIN);
}

// Round 15
// 1686.888 us; speedup vs baseline: 1.1205x; 1.1205x over previous
//
#include <hip/hip_runtime.h>
#include <hip/hip_bf16.h>
#include <stdint.h>

typedef __bf16 bf16;
typedef __bf16 bf16x8 __attribute__((ext_vector_type(8)));
typedef float f32x4 __attribute__((ext_vector_type(4)));

typedef uint32_t __attribute__((address_space(1))) * gptr_as1;
typedef uint32_t __attribute__((address_space(3))) * lptr_as3;

__device__ __forceinline__ void async16(const void* g, void* l) {
    __builtin_amdgcn_global_load_lds((gptr_as1)(uintptr_t)g,
                                     (lptr_as3)(uintptr_t)l,
                                     16, 0, 0);
}

__device__ __forceinline__ void bar() {
    asm volatile("" ::: "memory");
    __builtin_amdgcn_s_barrier();
    asm volatile("" ::: "memory");
}

// ---------------------------------------------------------------- cvt f32->bf16
__global__ void cvt_f32_bf16_kernel(const float* __restrict__ src,
                                    bf16* __restrict__ dst, int n8) {
    int i = blockIdx.x * blockDim.x + threadIdx.x;
    if (i >= n8) return;
    const float4* s = reinterpret_cast<const float4*>(src);
    float4 a = s[2 * (size_t)i], b = s[2 * (size_t)i + 1];
    bf16x8 v;
    v[0] = (bf16)a.x; v[1] = (bf16)a.y; v[2] = (bf16)a.z; v[3] = (bf16)a.w;
    v[4] = (bf16)b.x; v[5] = (bf16)b.y; v[6] = (bf16)b.z; v[7] = (bf16)b.w;
    *reinterpret_cast<bf16x8*>(dst + (size_t)i * 8) = v;
}

// cvt + 16-row interleave: src row r (of DHID) -> dst row (r/16)*32 + sel*16 + r%16.
__global__ void cvt_ilv_kernel(const float* __restrict__ src,
                               bf16* __restrict__ dst, int n8, int sel) {
    int i = blockIdx.x * blockDim.x + threadIdx.x;
    if (i >= n8) return;
    const int row = i >> 8;          // / 256  (DIN=2048 -> 256 chunks/row)
    const int c = i & 255;
    const int drow = ((row >> 4) << 5) + (sel << 4) + (row & 15);
    const float4* s = reinterpret_cast<const float4*>(src);
    float4 a = s[2 * (size_t)i], b = s[2 * (size_t)i + 1];
    bf16x8 v;
    v[0] = (bf16)a.x; v[1] = (bf16)a.y; v[2] = (bf16)a.z; v[3] = (bf16)a.w;
    v[4] = (bf16)b.x; v[5] = (bf16)b.y; v[6] = (bf16)b.z; v[7] = (bf16)b.w;
    *reinterpret_cast<bf16x8*>(dst + ((size_t)drow * 256 + c) * 8) = v;
}

// ---------------------------------------------------------------- 256^2 GEMM: wave-slip phases (ONE barrier/phase)
// C = A[M,K] * B[N,K]^T. 512 thr / 8 waves (2Mx4N), wave tile 128x64, BK=64.
// LDS 2dbuf x 64KB; R13's zero-VALU base+literal ds_reads; conflicts = 0.
// PHASE = [stage; reads; MFMA; (vmcnt); BARRIER] — reads first in program
// order (issue fast, queue into LDS pipe), NO mid-phase barrier: each wave's
// MFMA waits only on its OWN reads (compiler-counted lgkmcnt). Waves slip ->
// early-served waves' MFMA crunch overlaps later waves' LDS drain — the
// overlap the reads|BARRIER|MFMA lockstep forbade (R3..R13, all ~49%).
// Stage safety (one-barrier proof): stage into region R is safe iff R's last
// reads were SERVICED before the previous barrier — true because the reads'
// consuming MFMA (lgkm-gated) precedes that barrier in the reader's program
// order. Placement: P1 stages A-odd(kt+1)->nA   [last read P4(kt-1)];
//                   P4 stages B-h0,h1(kt+2)->cB [last read P3(kt)]
//                           + A-even(kt+2)->cA  [last read P3(kt); P4 reads
//                             A-odd rows — disjoint].
// FIFO: end-P4 outstanding = 6(kt+1 prologue-pattern) + 2(A-odd kt+1 @P1)
// + 6(kt+2 @P4) = 14 -> vmcnt(6) lands ALL of kt+1, leaves kt+2's 6.
// Tail: vmcnt(0) at NT-2. Prologue = R13 verbatim.
// EPI=0: bf16(gelu(acc*s1)) | EPI=1: f32(acc*s1) | EPI=2: swiglu, 16-col interleave.
template <int EPI, int K>
__global__ __launch_bounds__(512, 1)
void gemm8p(const bf16* __restrict__ A, const bf16* __restrict__ B,
            void* __restrict__ Cout, const float* __restrict__ s1p,
            const float* __restrict__ s2p, int N, int ldh) {
    __shared__ __align__(16) char sm[131072];

    const int tid = threadIdx.x;
    const int w = tid >> 6, l = tid & 63;
    const int wr = w >> 2, wc = w & 3;

    const int gx = gridDim.x;
    const int nwg = gx * (int)gridDim.y;
    const int orig = blockIdx.y * gx + blockIdx.x;
    const int wg = (orig & 7) * (nwg >> 3) + (orig >> 3);
    const int bm = wg / gx, bn = wg % gx;

    constexpr int NT = K / 64;

    f32x4 acc[8][4] = {};

    char* const bufA0 = sm;
    char* const bufB0 = sm + 32768;
    char* const bufA1 = sm + 65536;
    char* const bufB1 = sm + 98304;
    const int arow = bm * 256, brow = bn * 256;

    // staging (R13 verbatim): runtime addresses, builtin offset arg = 0
    const int srow_in = l >> 3;
    const int scolb = ((l & 7) ^ srow_in) << 4;
    auto STAGE = [&](char* ldsT, const bf16* g, int grow0, int kt, int r0) {
        const int rr = r0 + w * 8 + srow_in;
        const char* gp = (const char*)(g + (size_t)(grow0 + rr) * K + kt * 64) + scolb;
        async16(gp, ldsT + r0 * 128 + w * 1024);
    };

    // per-lane LDS read bases (loop-invariant; reads are base + literal)
    const int rlane = l & 15;
    const int chi = (l >> 4) << 4;
    const int sw = (rlane & 7) << 4;
    const int ksd = (rlane & 4) ? -64 : 64;          // (ks=1 col) - (ks=0 col)
    const int offA = (wr * 128 + rlane) * 128 + (chi ^ sw);
    const int offB = (wc * 64 + rlane) * 128 + (chi ^ sw);
    const char* const pA0  = bufA0 + offA;  const char* const pA0k = pA0 + ksd;
    const char* const pB0  = bufB0 + offB;  const char* const pB0k = pB0 + ksd;
    const char* const pA1  = bufA1 + offA;  const char* const pA1k = pA1 + ksd;
    const char* const pB1  = bufB1 + offB;  const char* const pB1k = pB1 + ksd;

    // ---- prologue: tile0 {A-even, B-h0, B-h1, A-odd}; tile1 {A-even, B-h0, B-h1}
    STAGE(bufA0, A, arow, 0, 0);   STAGE(bufA0, A, arow, 0, 128);  // A-even(0)
    STAGE(bufB0, B, brow, 0, 0);   STAGE(bufB0, B, brow, 0, 64);   // B-h0(0)
    STAGE(bufB0, B, brow, 0, 128); STAGE(bufB0, B, brow, 0, 192);  // B-h1(0)
    STAGE(bufA0, A, arow, 0, 64);  STAGE(bufA0, A, arow, 0, 192);  // A-odd(0)
    STAGE(bufA1, A, arow, 1, 0);   STAGE(bufA1, A, arow, 1, 128);  // A-even(1)
    STAGE(bufB1, B, brow, 1, 0);   STAGE(bufB1, B, brow, 1, 64);   // B-h0(1)
    STAGE(bufB1, B, brow, 1, 128); STAGE(bufB1, B, brow, 1, 192);  // B-h1(1)
    asm volatile("s_waitcnt vmcnt(6)" ::: "memory");
    bar();

    auto body = [&](int kt, char* cA, char* cB, char* nA,
                    const char* pa, const char* pak,
                    const char* pb, const char* pbk) {
        bf16x8 ae[4], ao[4], bv[4];
        // ---- P1: stage A-odd(kt+1)->nA; reads avE-ks0 + bv-ks0; MFMA; bar
        if (kt + 1 < NT) { STAGE(nA, A, arow, kt + 1, 64); STAGE(nA, A, arow, kt + 1, 192); }
#pragma unroll
        for (int i = 0; i < 4; ++i)
            ae[i] = *reinterpret_cast<const bf16x8*>(pa + i * 2048);
#pragma unroll
        for (int j = 0; j < 4; ++j)
            bv[j] = *reinterpret_cast<const bf16x8*>(pb + j * 2048);
        __builtin_amdgcn_s_setprio(1);
#pragma unroll
        for (int i = 0; i < 4; ++i)
#pragma unroll
            for (int j = 0; j < 4; ++j)
                acc[i][j] = __builtin_amdgcn_mfma_f32_16x16x32_bf16(ae[i], bv[j], acc[i][j], 0, 0, 0);
        __builtin_amdgcn_s_setprio(0);
        bar();
        // ---- P2: reads avO-ks0; MFMA; bar
#pragma unroll
        for (int i = 0; i < 4; ++i)
            ao[i] = *reinterpret_cast<const bf16x8*>(pa + 8192 + i * 2048);
        __builtin_amdgcn_s_setprio(1);
#pragma unroll
        for (int i = 0; i < 4; ++i)
#pragma unroll
            for (int j = 0; j < 4; ++j)
                acc[4 + i][j] = __builtin_amdgcn_mfma_f32_16x16x32_bf16(ao[i], bv[j], acc[4 + i][j], 0, 0, 0);
        __builtin_amdgcn_s_setprio(0);
        bar();
        // ---- P3: reads avE-ks1 + bv-ks1; MFMA; bar
#pragma unroll
        for (int i = 0; i < 4; ++i)
            ae[i] = *reinterpret_cast<const bf16x8*>(pak + i * 2048);
#pragma unroll
        for (int j = 0; j < 4; ++j)
            bv[j] = *reinterpret_cast<const bf16x8*>(pbk + j * 2048);
        __builtin_amdgcn_s_setprio(1);
#pragma unroll
        for (int i = 0; i < 4; ++i)
#pragma unroll
            for (int j = 0; j < 4; ++j)
                acc[i][j] = __builtin_amdgcn_mfma_f32_16x16x32_bf16(ae[i], bv[j], acc[i][j], 0, 0, 0);
        __builtin_amdgcn_s_setprio(0);
        bar();
        // ---- P4: stage B-h0,h1(kt+2)->cB + A-even(kt+2)->cA; reads avO-ks1; MFMA; vmcnt; bar
        if (kt + 2 < NT) {
            STAGE(cB, B, brow, kt + 2, 0);   STAGE(cB, B, brow, kt + 2, 64);
            STAGE(cB, B, brow, kt + 2, 128); STAGE(cB, B, brow, kt + 2, 192);
            STAGE(cA, A, arow, kt + 2, 0);   STAGE(cA, A, arow, kt + 2, 128);
        }
#pragma unroll
        for (int i = 0; i < 4; ++i)
            ao[i] = *reinterpret_cast<const bf16x8*>(pak + 8192 + i * 2048);
        __builtin_amdgcn_s_setprio(1);
#pragma unroll
        for (int i = 0; i < 4; ++i)
#pragma unroll
            for (int j = 0; j < 4; ++j)
                acc[4 + i][j] = __builtin_amdgcn_mfma_f32_16x16x32_bf16(ao[i], bv[j], acc[4 + i][j], 0, 0, 0);
        __builtin_amdgcn_s_setprio(0);
        if (kt == NT - 2) { asm volatile("s_waitcnt vmcnt(0)" ::: "memory"); }
        else              { asm volatile("s_waitcnt vmcnt(6)" ::: "memory"); }
        bar();
    };

#pragma unroll 1
    for (int kt = 0; kt < NT; kt += 2) {
        body(kt,     bufA0, bufB0, bufA1, pA0, pA0k, pB0, pB0k);
        body(kt + 1, bufA1, bufB1, bufA0, pA1, pA1k, pB1, pB1k);
    }

    const float s1 = s1p[0];
    const int r0 = bm * 256 + wr * 128 + ((l >> 4) << 2);
    if constexpr (EPI == 2) {
        const float s2 = s2p[0];
        const int hcb = (bn * 8 + wc * 2) * 16 + rlane;
#pragma unroll
        for (int i = 0; i < 8; ++i)
#pragma unroll
            for (int jp = 0; jp < 2; ++jp)
#pragma unroll
                for (int q = 0; q < 4; ++q) {
                    float g = acc[i][2 * jp][q] * s1;
                    float v = acc[i][2 * jp + 1][q] * s2;
                    float sig = 1.0f / (1.0f + __expf(-g));
                    ((bf16*)Cout)[(size_t)(r0 + i * 16 + q) * ldh + hcb + jp * 16] =
                        (bf16)(g * sig * v);
                }
    } else {
        const int c0 = bn * 256 + wc * 64 + rlane;
#pragma unroll
        for (int i = 0; i < 8; ++i)
#pragma unroll
            for (int j = 0; j < 4; ++j)
#pragma unroll
                for (int q = 0; q < 4; ++q) {
                    float v = acc[i][j][q] * s1;
                    size_t idx = (size_t)(r0 + i * 16 + q) * N + (c0 + j * 16);
                    if constexpr (EPI == 0) {
                        float g = 0.5f * v * (1.0f + erff(v * 0.70710678118654752f));
                        ((bf16*)Cout)[idx] = (bf16)g;
                    } else {
                        ((float*)Cout)[idx] = v;
                    }
                }
    }
}

// ---------------------------------------------------------------- launch
extern "C" void kernel_launch(void* const* d_in, const int* in_sizes, int n_in,
                              void* d_out, int out_size, void* d_ws, size_t ws_size,
                              hipStream_t stream) {
    constexpr int NTOK = 8192, DIN = 2048, DHID = 8192;

    const float* x  = (const float*)d_in[0];
    const float* W1 = (const float*)d_in[1];
    const float* W2 = (const float*)d_in[2];
    const float* Wh = (const float*)d_in[3];
    const float* W3 = (const float*)d_in[4];
    const float* s1 = (const float*)d_in[5];
    const float* s2 = (const float*)d_in[6];
    const float* sh = (const float*)d_in[7];
    const float* s3 = (const float*)d_in[8];
    float* out = (float*)d_out;

    char* ws = (char*)d_ws;
    size_t off = 0;
    bf16* xb   = (bf16*)(ws + off); off += (size_t)NTOK * DIN * 2;
    bf16* w12b = (bf16*)(ws + off); off += (size_t)2 * DHID * DIN * 2;
    bf16* w3b  = (bf16*)(ws + off); off += (size_t)DIN * DHID * 2;
    bf16* whb  = (bf16*)(ws + off); off += (size_t)DHID * DHID * 2;
    bf16* h1   = (bf16*)(ws + off); off += (size_t)NTOK * DHID * 2;
    bf16* h2   = (bf16*)(ws + off); off += (size_t)NTOK * DHID * 2;
    if (ws_size < off) return;

    auto cvt = [&](const float* s, bf16* d, size_t n) {
        int n8 = (int)(n / 8);
        cvt_f32_bf16_kernel<<<(n8 + 255) / 256, 256, 0, stream>>>(s, d, n8);
    };
    cvt(x,  xb,  (size_t)NTOK * DIN);
    cvt(Wh, whb, (size_t)DHID * DHID);
    cvt(W3, w3b, (size_t)DIN * DHID);
    {
        int n8 = (int)((size_t)DHID * DIN / 8);
        cvt_ilv_kernel<<<(n8 + 255) / 256, 256, 0, stream>>>(W1, w12b, n8, 0);
        cvt_ilv_kernel<<<(n8 + 255) / 256, 256, 0, stream>>>(W2, w12b, n8, 1);
    }

    // GEMM1+2 fused: C[8192, 16384] over interleaved W12, SwiGLU epilogue -> h1
    gemm8p<2, DIN><<<dim3(2 * DHID / 256, NTOK / 256), 512, 0, stream>>>(
        xb, w12b, h1, s1, s2, 2 * DHID, DHID);
    // hidden GEMM + gelu -> h2
    gemm8p<0, DHID><<<dim3(DHID / 256, NTOK / 256), 512, 0, stream>>>(
        h1, whb, h2, sh, sh, DHID, DHID);
    // output GEMM -> out (f32)
    gemm8p<1, DHID><<<dim3(DIN / 256, NTOK / 256), 512, 0, stream>>>(
        h2, w3b, out, s3, s3, DIN, DIN);
}